// Round 2
// baseline (150.117 us; speedup 1.0000x reference)
//
#include <hip/hip_runtime.h>
#include <hip/hip_bf16.h>

// Problem constants (B=1)
constexpr int T_LEN  = 262144;
constexpr int H      = 64;
constexpr int S_LEN  = 4;                  // R12: 8 -> 4. Doubles RNN wave count (2->4
                                           // waves/SIMD) to hide the ~5200cyc/step stall
                                           // seen in R11 counters; serial depth 24->20.
constexpr int WARM   = 16;                 // warm-up steps (R5: 20==26 bit-identical -> converged well before 20;
                                           // contraction ~0.56/step -> 0.56^16 ~ 9e-5 << bf16-h floor)
constexpr int CHUNKS = T_LEN / S_LEN;      // 65536
constexpr int NWAVE  = CHUNKS / 16;        // 4096 RNN waves
constexpr int PRE_STRIDE = 68;             // LDS row stride (mult of 4 -> b128-aligned rows)
constexpr int ZPAD_TAIL = 4;               // rows past T for harmless over-prefetch

typedef __attribute__((ext_vector_type(8))) short short8;  // 8 bf16 (4 VGPRs) MFMA A/B frag
typedef __attribute__((ext_vector_type(4))) float f32x4;   // MFMA C/D frag

// Saturation-safe fast tanh: 1 - 2/(exp(2x)+1). exp overflow -> rcp(inf)=0 -> 1. No NaN.
__device__ __forceinline__ float fast_tanh(float x) {
    float e = __expf(2.0f * x);
    return 1.0f - 2.0f * __builtin_amdgcn_rcpf(e + 1.0f);
}
// bf16 round-to-nearest-even pack / unpack (scalar fallback)
__device__ __forceinline__ unsigned short f2bf(float v) {
    unsigned u = __builtin_bit_cast(unsigned, v);
    return (unsigned short)((u + 0x7fffu + ((u >> 16) & 1u)) >> 16);
}
__device__ __forceinline__ float bf2f(unsigned short b) {
    return __builtin_bit_cast(float, (unsigned)b << 16);
}
// RNE pack of two floats -> packed bf16x2 (1-instruction v_cvt_pk_bf16_f32 when available)
__device__ __forceinline__ unsigned pack2(float a, float b) {
#if __has_builtin(__builtin_amdgcn_cvt_pk_bf16_f32)
    typedef __attribute__((ext_vector_type(2))) __bf16 bf16x2;
    bf16x2 r = __builtin_amdgcn_cvt_pk_bf16_f32(a, b);
    return __builtin_bit_cast(unsigned, r);
#else
    return (unsigned)f2bf(a) | ((unsigned)f2bf(b) << 16);
#endif
}

// ---------------------------------------------------------------------------
// K1: encoder (unchanged from R10 — validated). Weights staged once/block,
// wave-private scratch, no in-loop __syncthreads, Dekker-split L1, depth-1 x
// prefetch. Writes z at z_s (= z_pad + WARM rows), natural [t][64] RNE bf16.
// ---------------------------------------------------------------------------
__global__ __launch_bounds__(256) void encoder_kernel(
    const float* __restrict__ x,
    const float* __restrict__ W1, const float* __restrict__ b1,
    const float* __restrict__ W2, const float* __restrict__ b2,
    const float* __restrict__ Wx, const float* __restrict__ b_rnn,
    unsigned short* __restrict__ z_s, float* __restrict__ m_s)
{
    __shared__ uint4 w1f[4 * 64];
    __shared__ uint4 w2f[8 * 64];
    __shared__ uint4 w3f[8 * 64];
    __shared__ float pre_[4][16 * PRE_STRIDE];

    const int tid = threadIdx.x;
    const int w   = tid >> 6;
    const int l   = tid & 63;
    const int q   = l >> 4;
    const int l15 = l & 15;

    // ---- stage W2 / Wx / W1 as B-fragments (RNE bf16 weights) ----
    {
        const int n  = l;
        const int kg = w;
        float v2[16], v3[16];
        #pragma unroll
        for (int kk = 0; kk < 16; ++kk) {
            v2[kk] = W2[(kg * 16 + kk) * 64 + n];
            v3[kk] = Wx[(kg * 16 + kk) * 64 + n];
        }
        const int kh = kg >> 1;
        const int tn = n >> 4;
        #pragma unroll
        for (int s = 0; s < 2; ++s) {
            const int qq   = (2 * kg + s) & 3;
            const int lane = qq * 16 + (n & 15);
            uint4 o2, o3;
            o2.x = pack2(v2[s*8+0], v2[s*8+1]); o2.y = pack2(v2[s*8+2], v2[s*8+3]);
            o2.z = pack2(v2[s*8+4], v2[s*8+5]); o2.w = pack2(v2[s*8+6], v2[s*8+7]);
            o3.x = pack2(v3[s*8+0], v3[s*8+1]); o3.y = pack2(v3[s*8+2], v3[s*8+3]);
            o3.z = pack2(v3[s*8+4], v3[s*8+5]); o3.w = pack2(v3[s*8+6], v3[s*8+7]);
            w2f[(tn * 2 + kh) * 64 + lane] = o2;
            w3f[(tn * 2 + kh) * 64 + lane] = o3;
        }
        uint4 o1 = make_uint4(0, 0, 0, 0);
        if (q < 2) {
            float v1[8];
            #pragma unroll
            for (int j = 0; j < 8; ++j) v1[j] = W1[j * 64 + w * 16 + l15];
            o1.x = pack2(v1[0], v1[1]); o1.y = pack2(v1[2], v1[3]);
            o1.z = pack2(v1[4], v1[5]); o1.w = pack2(v1[6], v1[7]);
        }
        w1f[w * 64 + l] = o1;
    }
    __syncthreads();

    float b1v[4], b2v[4], brv[4];
    #pragma unroll
    for (int tn = 0; tn < 4; ++tn) {
        b1v[tn] = b1[tn * 16 + l15];
        b2v[tn] = b2[tn * 16 + l15];
        brv[tn] = b_rnn[tn * 16 + l15];
    }

    float* mypre = pre_[w];

    // prefetch iter 0's x
    float4 xa = make_float4(0.f, 0.f, 0.f, 0.f), xb = xa;
    if (q < 2) {
        const size_t t0 = (size_t)(blockIdx.x * 256 + w * 16 + l15) * 8;
        xa = *(const float4*)(x + t0);
        xb = *(const float4*)(x + t0 + 4);
    }

    #pragma unroll
    for (int it = 0; it < 4; ++it) {
        const int t0w = blockIdx.x * 256 + it * 64 + w * 16;

        // issue iter+1's x load NOW
        float4 na = xa, nb = xb;
        if (it < 3 && q < 2) {
            const size_t tn0 = (size_t)(t0w + 64 + l15) * 8;
            na = *(const float4*)(x + tn0);
            nb = *(const float4*)(x + tn0 + 4);
        }

        // ---- A1: Dekker-split x ----
        short8 a1 = (short8)0;
        if (q < 2) {
            const float xv[8] = {xa.x, xa.y, xa.z, xa.w, xb.x, xb.y, xb.z, xb.w};
            if (q == 0) {
                bool nz = false;
                #pragma unroll
                for (int d = 0; d < 8; ++d) nz = nz || (xv[d] != 0.0f);
                m_s[t0w + l15] = nz ? 1.0f : 0.0f;
                uint4 o;
                o.x = pack2(xv[0], xv[1]); o.y = pack2(xv[2], xv[3]);
                o.z = pack2(xv[4], xv[5]); o.w = pack2(xv[6], xv[7]);
                a1 = __builtin_bit_cast(short8, o);
            } else {
                float lo[8];
                #pragma unroll
                for (int d = 0; d < 8; ++d) lo[d] = xv[d] - bf2f(f2bf(xv[d]));
                uint4 o;
                o.x = pack2(lo[0], lo[1]); o.y = pack2(lo[2], lo[3]);
                o.z = pack2(lo[4], lo[5]); o.w = pack2(lo[6], lo[7]);
                a1 = __builtin_bit_cast(short8, o);
            }
        }

        // ---- L1 ----
        {
            f32x4 acc[4];
            #pragma unroll
            for (int tn = 0; tn < 4; ++tn)
                acc[tn] = __builtin_amdgcn_mfma_f32_16x16x32_bf16(
                    a1, __builtin_bit_cast(short8, w1f[tn * 64 + l]),
                    (f32x4){0.f, 0.f, 0.f, 0.f}, 0, 0, 0);
            #pragma unroll
            for (int tn = 0; tn < 4; ++tn)
                #pragma unroll
                for (int r = 0; r < 4; ++r)
                    mypre[(q * 4 + r) * PRE_STRIDE + tn * 16 + l15] =
                        fast_tanh(acc[tn][r] + b1v[tn]);
        }
        __builtin_amdgcn_wave_barrier();

        // ---- A2 ----
        short8 af[2];
        #pragma unroll
        for (int kh = 0; kh < 2; ++kh) {
            const uint4 r0 = *(const uint4*)(mypre + l15 * PRE_STRIDE + kh * 32 + q * 8);
            const uint4 r1 = *(const uint4*)(mypre + l15 * PRE_STRIDE + kh * 32 + q * 8 + 4);
            uint4 p;
            p.x = pack2(__builtin_bit_cast(float, r0.x), __builtin_bit_cast(float, r0.y));
            p.y = pack2(__builtin_bit_cast(float, r0.z), __builtin_bit_cast(float, r0.w));
            p.z = pack2(__builtin_bit_cast(float, r1.x), __builtin_bit_cast(float, r1.y));
            p.w = pack2(__builtin_bit_cast(float, r1.z), __builtin_bit_cast(float, r1.w));
            af[kh] = __builtin_bit_cast(short8, p);
        }
        __builtin_amdgcn_wave_barrier();

        // ---- L2 ----
        {
            f32x4 acc[4];
            #pragma unroll
            for (int tn = 0; tn < 4; ++tn) {
                f32x4 d = {0.f, 0.f, 0.f, 0.f};
                d = __builtin_amdgcn_mfma_f32_16x16x32_bf16(
                        af[0], __builtin_bit_cast(short8, w2f[(tn * 2 + 0) * 64 + l]), d, 0, 0, 0);
                d = __builtin_amdgcn_mfma_f32_16x16x32_bf16(
                        af[1], __builtin_bit_cast(short8, w2f[(tn * 2 + 1) * 64 + l]), d, 0, 0, 0);
                acc[tn] = d;
            }
            #pragma unroll
            for (int tn = 0; tn < 4; ++tn)
                #pragma unroll
                for (int r = 0; r < 4; ++r)
                    mypre[(q * 4 + r) * PRE_STRIDE + tn * 16 + l15] =
                        fast_tanh(acc[tn][r] + b2v[tn]);
        }
        __builtin_amdgcn_wave_barrier();

        // ---- A3 ----
        #pragma unroll
        for (int kh = 0; kh < 2; ++kh) {
            const uint4 r0 = *(const uint4*)(mypre + l15 * PRE_STRIDE + kh * 32 + q * 8);
            const uint4 r1 = *(const uint4*)(mypre + l15 * PRE_STRIDE + kh * 32 + q * 8 + 4);
            uint4 p;
            p.x = pack2(__builtin_bit_cast(float, r0.x), __builtin_bit_cast(float, r0.y));
            p.y = pack2(__builtin_bit_cast(float, r0.z), __builtin_bit_cast(float, r0.w));
            p.z = pack2(__builtin_bit_cast(float, r1.x), __builtin_bit_cast(float, r1.y));
            p.w = pack2(__builtin_bit_cast(float, r1.z), __builtin_bit_cast(float, r1.w));
            af[kh] = __builtin_bit_cast(short8, p);
        }
        __builtin_amdgcn_wave_barrier();

        // ---- L3 ----
        {
            f32x4 acc[4];
            #pragma unroll
            for (int tn = 0; tn < 4; ++tn) {
                f32x4 d = {0.f, 0.f, 0.f, 0.f};
                d = __builtin_amdgcn_mfma_f32_16x16x32_bf16(
                        af[0], __builtin_bit_cast(short8, w3f[(tn * 2 + 0) * 64 + l]), d, 0, 0, 0);
                d = __builtin_amdgcn_mfma_f32_16x16x32_bf16(
                        af[1], __builtin_bit_cast(short8, w3f[(tn * 2 + 1) * 64 + l]), d, 0, 0, 0);
                acc[tn] = d;
            }
            #pragma unroll
            for (int tn = 0; tn < 4; ++tn)
                #pragma unroll
                for (int r = 0; r < 4; ++r)
                    mypre[(q * 4 + r) * PRE_STRIDE + tn * 16 + l15] = acc[tn][r] + brv[tn];
        }
        __builtin_amdgcn_wave_barrier();

        // ---- out: z -> RNE bf16, natural [t][64] ----
        {
            const int ot = l >> 2;
            const int fq = l & 3;
            const float* src = mypre + ot * PRE_STRIDE + fq * 16;
            const uint4 r0 = *(const uint4*)(src + 0);
            const uint4 r1 = *(const uint4*)(src + 4);
            const uint4 r2 = *(const uint4*)(src + 8);
            const uint4 r3 = *(const uint4*)(src + 12);
            uint4 o0, o1;
            o0.x = pack2(__builtin_bit_cast(float, r0.x), __builtin_bit_cast(float, r0.y));
            o0.y = pack2(__builtin_bit_cast(float, r0.z), __builtin_bit_cast(float, r0.w));
            o0.z = pack2(__builtin_bit_cast(float, r1.x), __builtin_bit_cast(float, r1.y));
            o0.w = pack2(__builtin_bit_cast(float, r1.z), __builtin_bit_cast(float, r1.w));
            o1.x = pack2(__builtin_bit_cast(float, r2.x), __builtin_bit_cast(float, r2.y));
            o1.y = pack2(__builtin_bit_cast(float, r2.z), __builtin_bit_cast(float, r2.w));
            o1.z = pack2(__builtin_bit_cast(float, r3.x), __builtin_bit_cast(float, r3.y));
            o1.w = pack2(__builtin_bit_cast(float, r3.z), __builtin_bit_cast(float, r3.w));
            uint4* dst = (uint4*)(z_s + (size_t)(t0w + ot) * 64 + fq * 16);
            dst[0] = o0;
            dst[1] = o1;
        }
        __builtin_amdgcn_wave_barrier();

        xa = na; xb = nb;
    }
}

// ---------------------------------------------------------------------------
// K2 (R12): transposed RNN scan, S_LEN=4. Structure identical to R11 (in-reg
// bpermute transpose, f32 h state, parity double-buffer prefetch); only the
// chunking changed: 4096 waves x 20 steps instead of 2048 x 24. Rationale:
// R11 counters (MfmaUtil 4.9, Occ 19.4, VALUBusy 39, hbm 9%) showed a
// latency-bound serial scan with only 2 waves/SIMD — double the waves to
// hide the per-step stall, and shorten the serial chain 24->20.
// ---------------------------------------------------------------------------
__global__ __launch_bounds__(256) void rnn_kernel(
    const unsigned short* __restrict__ z_pad, const float* __restrict__ m_pad,
    const float* __restrict__ Wh, const float* __restrict__ Wm,
    const float* __restrict__ bm, float* __restrict__ out)
{
    const int tid = threadIdx.x;
    const int w   = tid >> 6;
    const int l   = tid & 63;
    const int q   = l >> 4;
    const int n15 = l & 15;
    const int rw  = blockIdx.x * 4 + w;   // global wave id
    const int c   = rw * 16 + n15;        // this lane's chunk (D/B col n = n15)

    // Wh^T A-fragments (persistent, RNE bf16) — same formula as old bfrag
    short8 afrag[8];
    #pragma unroll
    for (int tn = 0; tn < 4; ++tn) {
        #pragma unroll
        for (int kh = 0; kh < 2; ++kh) {
            short8 s;
            #pragma unroll
            for (int j = 0; j < 8; ++j)
                s[j] = (short)f2bf(Wh[(kh * 32 + q * 8 + j) * 64 + tn * 16 + n15]);
            afrag[tn * 2 + kh] = s;
        }
    }
    // Wm^T A-fragment: rows 0..3 valid (mean index), rest zero — same as old wmf
    short8 wmf[2];
    #pragma unroll
    for (int kh = 0; kh < 2; ++kh) {
        short8 s;
        #pragma unroll
        for (int j = 0; j < 8; ++j)
            s[j] = (n15 < 4) ? (short)f2bf(Wm[(kh * 32 + q * 8 + j) * 4 + n15]) : (short)0;
        wmf[kh] = s;
    }
    const float4 bmv = *(const float4*)bm;   // bm[0..3], used by q==0 lanes

    // h state: f32 D-layout hst[tn][r] = h[chunk n15][feat tn*16+q*4+r];
    // hB = bf16 B-frags of h^T (rebuilt from hst each step)
    f32x4 hst[4];
    #pragma unroll
    for (int tn = 0; tn < 4; ++tn) hst[tn] = (f32x4){0.f, 0.f, 0.f, 0.f};
    short8 hB[2];
    hB[0] = (short8)0;
    hB[1] = (short8)0;

    // bpermute pull indices (bytes): src lane = (2*(q&1) + (d>>1))*16 + n15
    const int idxA = ((2 * (q & 1) + 0) * 16 + n15) * 4;   // dwords d = 0,1
    const int idxB = ((2 * (q & 1) + 1) * 16 + n15) * 4;   // dwords d = 2,3
    const bool hiSel = (q >= 2);                           // reg = P[2kh + (q>>1)]

    // per-lane linear pointers into the PADDED arrays (padded row 0 = abs t -WARM)
    const unsigned short* zrow = z_pad + (size_t)c * S_LEN * 64;
    const float*          mrow = m_pad + (size_t)c * S_LEN;
    const int tneg = -(c * S_LEN);        // st at which abs t == 0 (only low chunks of wave 0 reachable)

    // preload steps st=-WARM (parity 0) and st=-WARM+1 (parity 1)
    // z per step: 4 x uint2, tn-th = feats [tn*16+q*4 .. +4) of this chunk's row
    uint2 zb0[4], zb1[4];
    float mb0, mb1;
    #pragma unroll
    for (int tn = 0; tn < 4; ++tn) {
        zb0[tn] = *(const uint2*)(zrow + tn * 16 + q * 4);
        zb1[tn] = *(const uint2*)(zrow + 64 + tn * 16 + q * 4);
    }
    mb0 = mrow[0];
    mb1 = mrow[1];
    zrow += 128; mrow += 2;               // -> reload row for st=-WARM (i.e. st+2)

    // body: consume (zbuf,mref) for step st, then reload them from (zrl,mrl) = st+2
    auto body = [&](uint2* zbuf, float& mref,
                    const unsigned short* zrl, const float* mrl,
                    int stv, bool means_prev, bool may_reset) {
        if (may_reset && rw == 0) {       // uniform branch: 4095/4096 waves skip
            if (stv == tneg) {            // per-lane (tneg depends on n15)
                hB[0] = (short8)0; hB[1] = (short8)0;
                #pragma unroll
                for (int tn = 0; tn < 4; ++tn) hst[tn] = (f32x4){0.f, 0.f, 0.f, 0.f};
            }
        }
        // preact^T = Wh^T @ h^T  (D: rows = feats q*4+r within tile mt, col = chunk n15)
        f32x4 acc[4];
        #pragma unroll
        for (int mt = 0; mt < 4; ++mt) {
            f32x4 d = {0.f, 0.f, 0.f, 0.f};
            d = __builtin_amdgcn_mfma_f32_16x16x32_bf16(afrag[mt * 2 + 0], hB[0], d, 0, 0, 0);
            d = __builtin_amdgcn_mfma_f32_16x16x32_bf16(afrag[mt * 2 + 1], hB[1], d, 0, 0, 0);
            acc[mt] = d;
        }
        // means of the PREVIOUS step's h (hB not yet updated):
        // D rows 0..3 = mean idx -> q==0 lanes hold means[0..3][chunk n15]
        if (means_prev) {
            f32x4 a2 = {0.f, 0.f, 0.f, 0.f};
            a2 = __builtin_amdgcn_mfma_f32_16x16x32_bf16(wmf[0], hB[0], a2, 0, 0, 0);
            a2 = __builtin_amdgcn_mfma_f32_16x16x32_bf16(wmf[1], hB[1], a2, 0, 0, 0);
            if (q == 0) {
                const size_t tp = (size_t)c * S_LEN + (stv - 1);
                *(float4*)(out + tp * 4) =
                    make_float4(a2[0] + bmv.x, a2[1] + bmv.y, a2[2] + bmv.z, a2[3] + bmv.w);
            }
        }
        // z add + tanh + mask-carry, all in-register (f32 state)
        const bool upd = (mref != 0.0f);
        #pragma unroll
        for (int tn = 0; tn < 4; ++tn) {
            const unsigned short* zp = (const unsigned short*)&zbuf[tn];
            #pragma unroll
            for (int r = 0; r < 4; ++r) {
                const float nv = fast_tanh(acc[tn][r] + bf2f(zp[r]));
                hst[tn][r] = upd ? nv : hst[tn][r];
            }
        }
        // rebuild h^T B-frags: pack pairs, then dword-level bpermute transpose.
        // target (q,n15) frag kh dword d <- P[2kh+(q>>1)][d&1] of lane (2(q&1)+(d>>1))*16+n15
        unsigned P[4][2];
        #pragma unroll
        for (int tn = 0; tn < 4; ++tn) {
            P[tn][0] = pack2(hst[tn][0], hst[tn][1]);
            P[tn][1] = pack2(hst[tn][2], hst[tn][3]);
        }
        #pragma unroll
        for (int kh = 0; kh < 2; ++kh) {
            unsigned fd[4];
            #pragma unroll
            for (int d = 0; d < 4; ++d) {
                const int idx = (d < 2) ? idxA : idxB;
                const unsigned lo =
                    (unsigned)__builtin_amdgcn_ds_bpermute(idx, (int)P[2 * kh + 0][d & 1]);
                const unsigned hi =
                    (unsigned)__builtin_amdgcn_ds_bpermute(idx, (int)P[2 * kh + 1][d & 1]);
                fd[d] = hiSel ? hi : lo;
            }
            uint4 u = make_uint4(fd[0], fd[1], fd[2], fd[3]);
            hB[kh] = __builtin_bit_cast(short8, u);
        }
        // reload this parity's buffers for step st+2 (wait lands a full body later)
        #pragma unroll
        for (int tn = 0; tn < 4; ++tn)
            zbuf[tn] = *(const uint2*)(zrl + tn * 16 + q * 4);
        mref = mrl[0];
    };

    // ---- warm loop: 16 steps, parity-pair per iteration ----
    for (int i = 0; i < WARM / 2; ++i) {
        const int st = -WARM + 2 * i;
        body(zb0, mb0, zrow,      mrow,     st,     false, true);
        body(zb1, mb1, zrow + 64, mrow + 1, st + 1, false, true);
        zrow += 128; mrow += 2;
    }

    // ---- main loop: 4 steps, fully unrolled ----
    #pragma unroll
    for (int st = 0; st < S_LEN; ++st) {
        if ((st & 1) == 0)
            body(zb0, mb0, zrow + st * 64, mrow + st, st, st >= 1, st == 0);
        else
            body(zb1, mb1, zrow + st * 64, mrow + st, st, true, false);
    }

    // tail flush: means for step S_LEN-1
    {
        f32x4 a2 = {0.f, 0.f, 0.f, 0.f};
        a2 = __builtin_amdgcn_mfma_f32_16x16x32_bf16(wmf[0], hB[0], a2, 0, 0, 0);
        a2 = __builtin_amdgcn_mfma_f32_16x16x32_bf16(wmf[1], hB[1], a2, 0, 0, 0);
        if (q == 0) {
            const size_t tp = (size_t)c * S_LEN + (S_LEN - 1);
            *(float4*)(out + tp * 4) =
                make_float4(a2[0] + bmv.x, a2[1] + bmv.y, a2[2] + bmv.z, a2[3] + bmv.w);
        }
    }
}

extern "C" void kernel_launch(void* const* d_in, const int* in_sizes, int n_in,
                              void* d_out, int out_size, void* d_ws, size_t ws_size,
                              hipStream_t stream) {
    const float* x     = (const float*)d_in[0];
    const float* W1    = (const float*)d_in[1];
    const float* b1    = (const float*)d_in[2];
    const float* W2    = (const float*)d_in[3];
    const float* b2    = (const float*)d_in[4];
    const float* Wx    = (const float*)d_in[5];
    const float* Wh    = (const float*)d_in[6];
    const float* b_rnn = (const float*)d_in[7];
    const float* Wm    = (const float*)d_in[8];
    const float* bm    = (const float*)d_in[9];
    float* out = (float*)d_out;

    // Workspace layout (front-padded by WARM rows; pad contents = poison, OK):
    //   z_pad: (WARM + T + ZPAD_TAIL) rows x 64 bf16
    //   m_pad: (WARM + T + ZPAD_TAIL) floats
    unsigned short* z_pad = (unsigned short*)d_ws;
    const size_t z_rows   = (size_t)(WARM + T_LEN + ZPAD_TAIL);
    float*          m_pad = (float*)((char*)d_ws + z_rows * H * 2);

    unsigned short* z_s = z_pad + (size_t)WARM * H;   // abs t=0 row
    float*          m_s = m_pad + WARM;

    encoder_kernel<<<T_LEN / 256, 256, 0, stream>>>(x, W1, b1, W2, b2, Wx, b_rnn, z_s, m_s);
    rnn_kernel<<<NWAVE / 4, 256, 0, stream>>>(z_pad, m_pad, Wh, Wm, bm, out);
}

// Round 3
// 129.863 us; speedup vs baseline: 1.1560x; 1.1560x over previous
//
#include <hip/hip_runtime.h>
#include <hip/hip_bf16.h>

// Problem constants (B=1)
constexpr int T_LEN  = 262144;
constexpr int H      = 64;
constexpr int S_LEN  = 8;                  // R13: revert R12's S=4 (A/B showed x1.67 warm work
                                           // beats the +36% TLP throughput gain -> net loss)
constexpr int WARM   = 16;                 // warm-up steps (R5: 20==26 bit-identical -> converged well before 20;
                                           // contraction ~0.56/step -> 0.56^16 ~ 9e-5 << bf16-h floor)
constexpr int CHUNKS = T_LEN / S_LEN;      // 32768
constexpr int NWAVE  = CHUNKS / 16;        // 2048 RNN waves
constexpr int PRE_STRIDE = 68;             // LDS row stride (mult of 4 -> b128-aligned rows)
constexpr int ZPAD_TAIL = 4;               // rows past T for harmless over-prefetch

typedef __attribute__((ext_vector_type(8))) short short8;  // 8 bf16 (4 VGPRs) MFMA A/B frag
typedef __attribute__((ext_vector_type(4))) float f32x4;   // MFMA C/D frag

// Saturation-safe fast tanh: 1 - 2/(exp(2x)+1). exp overflow -> rcp(inf)=0 -> 1. No NaN.
__device__ __forceinline__ float fast_tanh(float x) {
    float e = __expf(2.0f * x);
    return 1.0f - 2.0f * __builtin_amdgcn_rcpf(e + 1.0f);
}
// bf16 round-to-nearest-even pack / unpack (scalar fallback)
__device__ __forceinline__ unsigned short f2bf(float v) {
    unsigned u = __builtin_bit_cast(unsigned, v);
    return (unsigned short)((u + 0x7fffu + ((u >> 16) & 1u)) >> 16);
}
__device__ __forceinline__ float bf2f(unsigned short b) {
    return __builtin_bit_cast(float, (unsigned)b << 16);
}
// RNE pack of two floats -> packed bf16x2 (1-instruction v_cvt_pk_bf16_f32 when available)
__device__ __forceinline__ unsigned pack2(float a, float b) {
#if __has_builtin(__builtin_amdgcn_cvt_pk_bf16_f32)
    typedef __attribute__((ext_vector_type(2))) __bf16 bf16x2;
    bf16x2 r = __builtin_amdgcn_cvt_pk_bf16_f32(a, b);
    return __builtin_bit_cast(unsigned, r);
#else
    return (unsigned)f2bf(a) | ((unsigned)f2bf(b) << 16);
#endif
}

// ---------------------------------------------------------------------------
// K1: encoder (unchanged from R10 — validated). Weights staged once/block,
// wave-private scratch, no in-loop __syncthreads, Dekker-split L1, depth-1 x
// prefetch. Writes z at z_s (= z_pad + WARM rows), natural [t][64] RNE bf16.
// ---------------------------------------------------------------------------
__global__ __launch_bounds__(256) void encoder_kernel(
    const float* __restrict__ x,
    const float* __restrict__ W1, const float* __restrict__ b1,
    const float* __restrict__ W2, const float* __restrict__ b2,
    const float* __restrict__ Wx, const float* __restrict__ b_rnn,
    unsigned short* __restrict__ z_s, float* __restrict__ m_s)
{
    __shared__ uint4 w1f[4 * 64];
    __shared__ uint4 w2f[8 * 64];
    __shared__ uint4 w3f[8 * 64];
    __shared__ float pre_[4][16 * PRE_STRIDE];

    const int tid = threadIdx.x;
    const int w   = tid >> 6;
    const int l   = tid & 63;
    const int q   = l >> 4;
    const int l15 = l & 15;

    // ---- stage W2 / Wx / W1 as B-fragments (RNE bf16 weights) ----
    {
        const int n  = l;
        const int kg = w;
        float v2[16], v3[16];
        #pragma unroll
        for (int kk = 0; kk < 16; ++kk) {
            v2[kk] = W2[(kg * 16 + kk) * 64 + n];
            v3[kk] = Wx[(kg * 16 + kk) * 64 + n];
        }
        const int kh = kg >> 1;
        const int tn = n >> 4;
        #pragma unroll
        for (int s = 0; s < 2; ++s) {
            const int qq   = (2 * kg + s) & 3;
            const int lane = qq * 16 + (n & 15);
            uint4 o2, o3;
            o2.x = pack2(v2[s*8+0], v2[s*8+1]); o2.y = pack2(v2[s*8+2], v2[s*8+3]);
            o2.z = pack2(v2[s*8+4], v2[s*8+5]); o2.w = pack2(v2[s*8+6], v2[s*8+7]);
            o3.x = pack2(v3[s*8+0], v3[s*8+1]); o3.y = pack2(v3[s*8+2], v3[s*8+3]);
            o3.z = pack2(v3[s*8+4], v3[s*8+5]); o3.w = pack2(v3[s*8+6], v3[s*8+7]);
            w2f[(tn * 2 + kh) * 64 + lane] = o2;
            w3f[(tn * 2 + kh) * 64 + lane] = o3;
        }
        uint4 o1 = make_uint4(0, 0, 0, 0);
        if (q < 2) {
            float v1[8];
            #pragma unroll
            for (int j = 0; j < 8; ++j) v1[j] = W1[j * 64 + w * 16 + l15];
            o1.x = pack2(v1[0], v1[1]); o1.y = pack2(v1[2], v1[3]);
            o1.z = pack2(v1[4], v1[5]); o1.w = pack2(v1[6], v1[7]);
        }
        w1f[w * 64 + l] = o1;
    }
    __syncthreads();

    float b1v[4], b2v[4], brv[4];
    #pragma unroll
    for (int tn = 0; tn < 4; ++tn) {
        b1v[tn] = b1[tn * 16 + l15];
        b2v[tn] = b2[tn * 16 + l15];
        brv[tn] = b_rnn[tn * 16 + l15];
    }

    float* mypre = pre_[w];

    // prefetch iter 0's x
    float4 xa = make_float4(0.f, 0.f, 0.f, 0.f), xb = xa;
    if (q < 2) {
        const size_t t0 = (size_t)(blockIdx.x * 256 + w * 16 + l15) * 8;
        xa = *(const float4*)(x + t0);
        xb = *(const float4*)(x + t0 + 4);
    }

    #pragma unroll
    for (int it = 0; it < 4; ++it) {
        const int t0w = blockIdx.x * 256 + it * 64 + w * 16;

        // issue iter+1's x load NOW
        float4 na = xa, nb = xb;
        if (it < 3 && q < 2) {
            const size_t tn0 = (size_t)(t0w + 64 + l15) * 8;
            na = *(const float4*)(x + tn0);
            nb = *(const float4*)(x + tn0 + 4);
        }

        // ---- A1: Dekker-split x ----
        short8 a1 = (short8)0;
        if (q < 2) {
            const float xv[8] = {xa.x, xa.y, xa.z, xa.w, xb.x, xb.y, xb.z, xb.w};
            if (q == 0) {
                bool nz = false;
                #pragma unroll
                for (int d = 0; d < 8; ++d) nz = nz || (xv[d] != 0.0f);
                m_s[t0w + l15] = nz ? 1.0f : 0.0f;
                uint4 o;
                o.x = pack2(xv[0], xv[1]); o.y = pack2(xv[2], xv[3]);
                o.z = pack2(xv[4], xv[5]); o.w = pack2(xv[6], xv[7]);
                a1 = __builtin_bit_cast(short8, o);
            } else {
                float lo[8];
                #pragma unroll
                for (int d = 0; d < 8; ++d) lo[d] = xv[d] - bf2f(f2bf(xv[d]));
                uint4 o;
                o.x = pack2(lo[0], lo[1]); o.y = pack2(lo[2], lo[3]);
                o.z = pack2(lo[4], lo[5]); o.w = pack2(lo[6], lo[7]);
                a1 = __builtin_bit_cast(short8, o);
            }
        }

        // ---- L1 ----
        {
            f32x4 acc[4];
            #pragma unroll
            for (int tn = 0; tn < 4; ++tn)
                acc[tn] = __builtin_amdgcn_mfma_f32_16x16x32_bf16(
                    a1, __builtin_bit_cast(short8, w1f[tn * 64 + l]),
                    (f32x4){0.f, 0.f, 0.f, 0.f}, 0, 0, 0);
            #pragma unroll
            for (int tn = 0; tn < 4; ++tn)
                #pragma unroll
                for (int r = 0; r < 4; ++r)
                    mypre[(q * 4 + r) * PRE_STRIDE + tn * 16 + l15] =
                        fast_tanh(acc[tn][r] + b1v[tn]);
        }
        __builtin_amdgcn_wave_barrier();

        // ---- A2 ----
        short8 af[2];
        #pragma unroll
        for (int kh = 0; kh < 2; ++kh) {
            const uint4 r0 = *(const uint4*)(mypre + l15 * PRE_STRIDE + kh * 32 + q * 8);
            const uint4 r1 = *(const uint4*)(mypre + l15 * PRE_STRIDE + kh * 32 + q * 8 + 4);
            uint4 p;
            p.x = pack2(__builtin_bit_cast(float, r0.x), __builtin_bit_cast(float, r0.y));
            p.y = pack2(__builtin_bit_cast(float, r0.z), __builtin_bit_cast(float, r0.w));
            p.z = pack2(__builtin_bit_cast(float, r1.x), __builtin_bit_cast(float, r1.y));
            p.w = pack2(__builtin_bit_cast(float, r1.z), __builtin_bit_cast(float, r1.w));
            af[kh] = __builtin_bit_cast(short8, p);
        }
        __builtin_amdgcn_wave_barrier();

        // ---- L2 ----
        {
            f32x4 acc[4];
            #pragma unroll
            for (int tn = 0; tn < 4; ++tn) {
                f32x4 d = {0.f, 0.f, 0.f, 0.f};
                d = __builtin_amdgcn_mfma_f32_16x16x32_bf16(
                        af[0], __builtin_bit_cast(short8, w2f[(tn * 2 + 0) * 64 + l]), d, 0, 0, 0);
                d = __builtin_amdgcn_mfma_f32_16x16x32_bf16(
                        af[1], __builtin_bit_cast(short8, w2f[(tn * 2 + 1) * 64 + l]), d, 0, 0, 0);
                acc[tn] = d;
            }
            #pragma unroll
            for (int tn = 0; tn < 4; ++tn)
                #pragma unroll
                for (int r = 0; r < 4; ++r)
                    mypre[(q * 4 + r) * PRE_STRIDE + tn * 16 + l15] =
                        fast_tanh(acc[tn][r] + b2v[tn]);
        }
        __builtin_amdgcn_wave_barrier();

        // ---- A3 ----
        #pragma unroll
        for (int kh = 0; kh < 2; ++kh) {
            const uint4 r0 = *(const uint4*)(mypre + l15 * PRE_STRIDE + kh * 32 + q * 8);
            const uint4 r1 = *(const uint4*)(mypre + l15 * PRE_STRIDE + kh * 32 + q * 8 + 4);
            uint4 p;
            p.x = pack2(__builtin_bit_cast(float, r0.x), __builtin_bit_cast(float, r0.y));
            p.y = pack2(__builtin_bit_cast(float, r0.z), __builtin_bit_cast(float, r0.w));
            p.z = pack2(__builtin_bit_cast(float, r1.x), __builtin_bit_cast(float, r1.y));
            p.w = pack2(__builtin_bit_cast(float, r1.z), __builtin_bit_cast(float, r1.w));
            af[kh] = __builtin_bit_cast(short8, p);
        }
        __builtin_amdgcn_wave_barrier();

        // ---- L3 ----
        {
            f32x4 acc[4];
            #pragma unroll
            for (int tn = 0; tn < 4; ++tn) {
                f32x4 d = {0.f, 0.f, 0.f, 0.f};
                d = __builtin_amdgcn_mfma_f32_16x16x32_bf16(
                        af[0], __builtin_bit_cast(short8, w3f[(tn * 2 + 0) * 64 + l]), d, 0, 0, 0);
                d = __builtin_amdgcn_mfma_f32_16x16x32_bf16(
                        af[1], __builtin_bit_cast(short8, w3f[(tn * 2 + 1) * 64 + l]), d, 0, 0, 0);
                acc[tn] = d;
            }
            #pragma unroll
            for (int tn = 0; tn < 4; ++tn)
                #pragma unroll
                for (int r = 0; r < 4; ++r)
                    mypre[(q * 4 + r) * PRE_STRIDE + tn * 16 + l15] = acc[tn][r] + brv[tn];
        }
        __builtin_amdgcn_wave_barrier();

        // ---- out: z -> RNE bf16, natural [t][64] ----
        {
            const int ot = l >> 2;
            const int fq = l & 3;
            const float* src = mypre + ot * PRE_STRIDE + fq * 16;
            const uint4 r0 = *(const uint4*)(src + 0);
            const uint4 r1 = *(const uint4*)(src + 4);
            const uint4 r2 = *(const uint4*)(src + 8);
            const uint4 r3 = *(const uint4*)(src + 12);
            uint4 o0, o1;
            o0.x = pack2(__builtin_bit_cast(float, r0.x), __builtin_bit_cast(float, r0.y));
            o0.y = pack2(__builtin_bit_cast(float, r0.z), __builtin_bit_cast(float, r0.w));
            o0.z = pack2(__builtin_bit_cast(float, r1.x), __builtin_bit_cast(float, r1.y));
            o0.w = pack2(__builtin_bit_cast(float, r1.z), __builtin_bit_cast(float, r1.w));
            o1.x = pack2(__builtin_bit_cast(float, r2.x), __builtin_bit_cast(float, r2.y));
            o1.y = pack2(__builtin_bit_cast(float, r2.z), __builtin_bit_cast(float, r2.w));
            o1.z = pack2(__builtin_bit_cast(float, r3.x), __builtin_bit_cast(float, r3.y));
            o1.w = pack2(__builtin_bit_cast(float, r3.z), __builtin_bit_cast(float, r3.w));
            uint4* dst = (uint4*)(z_s + (size_t)(t0w + ot) * 64 + fq * 16);
            dst[0] = o0;
            dst[1] = o1;
        }
        __builtin_amdgcn_wave_barrier();

        xa = na; xb = nb;
    }
}

// ---------------------------------------------------------------------------
// K2 (R13): transposed RNN scan with FEATURE-PERMUTED weights — no transpose
// on the serial path. Wh's output rows are pre-permuted by
//   pi(16*tn + 4*q + r) = 32*(tn>>1) + 8*q + 4*(tn&1) + r
// so that the packed (pack2) MFMA D output of lane (q,n15) lands EXACTLY in
// B-fragment k-slot order: hB[half] element j = h-feature (half*32 + 8q + j).
// The per-step body is now: 8 MFMA -> add z (pi-offset loads) -> tanh ->
// pack2 -> 8 packed cndmask (mask-carry) -> next MFMA. The 16 ds_bpermute,
// 8 select-cndmasks and the f32 hst state of R11/R12 are gone. Arithmetic is
// bit-identical (same k-order summation); absmax must stay 0.001464844.
// Rationale: R12 A/B showed the scan is ~half VALU-issue-bound at 4 w/SIMD
// (VALUBusy 57%) — cut per-step issue instead of adding TLP.
// ---------------------------------------------------------------------------
__global__ __launch_bounds__(256) void rnn_kernel(
    const unsigned short* __restrict__ z_pad, const float* __restrict__ m_pad,
    const float* __restrict__ Wh, const float* __restrict__ Wm,
    const float* __restrict__ bm, float* __restrict__ out)
{
    const int tid = threadIdx.x;
    const int w   = tid >> 6;
    const int l   = tid & 63;
    const int q   = l >> 4;
    const int n15 = l & 15;
    const int rw  = blockIdx.x * 4 + w;   // global wave id
    const int c   = rw * 16 + n15;        // this lane's chunk (D/B col n = n15)

    // pi-permuted Wh^T A-fragments: A[16*mt + rr][k] = Wh[k][pi(16*mt + rr)],
    // rr = n15 (A-frag row-within-tile = lane&15), k = kh*32 + q*8 + j.
    short8 afrag[8];
    #pragma unroll
    for (int tn = 0; tn < 4; ++tn) {
        const int prow = 32 * (tn >> 1) + 8 * (n15 >> 2) + 4 * (tn & 1) + (n15 & 3);
        #pragma unroll
        for (int kh = 0; kh < 2; ++kh) {
            short8 s;
            #pragma unroll
            for (int j = 0; j < 8; ++j)
                s[j] = (short)f2bf(Wh[(kh * 32 + q * 8 + j) * 64 + prow]);
            afrag[tn * 2 + kh] = s;
        }
    }
    // Wm^T A-fragment: rows 0..3 valid (mean index), rest zero. UNCHANGED:
    // hB's k-slot order is standard-feature order, so Wm needs no permutation.
    short8 wmf[2];
    #pragma unroll
    for (int kh = 0; kh < 2; ++kh) {
        short8 s;
        #pragma unroll
        for (int j = 0; j < 8; ++j)
            s[j] = (n15 < 4) ? (short)f2bf(Wm[(kh * 32 + q * 8 + j) * 4 + n15]) : (short)0;
        wmf[kh] = s;
    }
    const float4 bmv = *(const float4*)bm;   // bm[0..3], used by q==0 lanes

    // h state: ONLY the bf16 B-frags. hB[half] element j = h[chunk n15][feat half*32+8q+j].
    short8 hB[2];
    hB[0] = (short8)0;
    hB[1] = (short8)0;

    // per-lane linear pointers into the PADDED arrays (padded row 0 = abs t -WARM)
    const unsigned short* zrow = z_pad + (size_t)c * S_LEN * 64;
    const float*          mrow = m_pad + (size_t)c * S_LEN;
    const int tneg = -(c * S_LEN);        // st at which abs t == 0 (only low chunks of wave 0 reachable)

    // z load offset for acc-tile tn under pi: feat base = 32*(tn>>1) + 8q + 4*(tn&1)
    const int zo0 = 8 * q;            // tn=0
    const int zo1 = 8 * q + 4;        // tn=1
    const int zo2 = 8 * q + 32;       // tn=2
    const int zo3 = 8 * q + 36;       // tn=3

    // preload steps st=-WARM (parity 0) and st=-WARM+1 (parity 1)
    uint2 zb0[4], zb1[4];
    float mb0, mb1;
    {
        zb0[0] = *(const uint2*)(zrow + zo0);
        zb0[1] = *(const uint2*)(zrow + zo1);
        zb0[2] = *(const uint2*)(zrow + zo2);
        zb0[3] = *(const uint2*)(zrow + zo3);
        zb1[0] = *(const uint2*)(zrow + 64 + zo0);
        zb1[1] = *(const uint2*)(zrow + 64 + zo1);
        zb1[2] = *(const uint2*)(zrow + 64 + zo2);
        zb1[3] = *(const uint2*)(zrow + 64 + zo3);
    }
    mb0 = mrow[0];
    mb1 = mrow[1];
    zrow += 128; mrow += 2;               // -> reload row for st=-WARM (i.e. st+2)

    // body: consume (zbuf,mref) for step st, then reload them from (zrl,mrl) = st+2
    auto body = [&](uint2* zbuf, float& mref,
                    const unsigned short* zrl, const float* mrl,
                    int stv, bool means_prev, bool may_reset) {
        if (may_reset && rw == 0) {       // uniform branch: 2047/2048 waves skip
            if (stv == tneg) {            // per-lane (tneg depends on n15)
                hB[0] = (short8)0; hB[1] = (short8)0;
            }
        }
        // preact^T(pi) = pi-rows(Wh^T) @ h^T
        f32x4 acc[4];
        #pragma unroll
        for (int mt = 0; mt < 4; ++mt) {
            f32x4 d = {0.f, 0.f, 0.f, 0.f};
            d = __builtin_amdgcn_mfma_f32_16x16x32_bf16(afrag[mt * 2 + 0], hB[0], d, 0, 0, 0);
            d = __builtin_amdgcn_mfma_f32_16x16x32_bf16(afrag[mt * 2 + 1], hB[1], d, 0, 0, 0);
            acc[mt] = d;
        }
        // means of the PREVIOUS step's h (hB not yet updated):
        // D rows 0..3 = mean idx -> q==0 lanes hold means[0..3][chunk n15]
        if (means_prev) {
            f32x4 a2 = {0.f, 0.f, 0.f, 0.f};
            a2 = __builtin_amdgcn_mfma_f32_16x16x32_bf16(wmf[0], hB[0], a2, 0, 0, 0);
            a2 = __builtin_amdgcn_mfma_f32_16x16x32_bf16(wmf[1], hB[1], a2, 0, 0, 0);
            if (q == 0) {
                const size_t tp = (size_t)c * S_LEN + (stv - 1);
                *(float4*)(out + tp * 4) =
                    make_float4(a2[0] + bmv.x, a2[1] + bmv.y, a2[2] + bmv.z, a2[3] + bmv.w);
            }
        }
        // z add + tanh + pack straight into hB; mask-carry on packed words.
        // acc[tn][r] is feature pi(16tn+4q+r) = zoff(tn)+r -> zbuf[tn] shorts [r].
        // Dest: hB[tn>>1] dword (tn&1)*2 + {0,1}.
        const bool upd = (mref != 0.0f);
        #pragma unroll
        for (int tn = 0; tn < 4; ++tn) {
            const unsigned short* zp = (const unsigned short*)&zbuf[tn];
            float th[4];
            #pragma unroll
            for (int r = 0; r < 4; ++r)
                th[r] = fast_tanh(acc[tn][r] + bf2f(zp[r]));
            const unsigned w0 = pack2(th[0], th[1]);
            const unsigned w1 = pack2(th[2], th[3]);
            unsigned* hw = (unsigned*)&hB[tn >> 1];
            const int wi = (tn & 1) * 2;
            hw[wi + 0] = upd ? w0 : hw[wi + 0];
            hw[wi + 1] = upd ? w1 : hw[wi + 1];
        }
        // reload this parity's buffers for step st+2 (wait lands a full body later)
        zbuf[0] = *(const uint2*)(zrl + zo0);
        zbuf[1] = *(const uint2*)(zrl + zo1);
        zbuf[2] = *(const uint2*)(zrl + zo2);
        zbuf[3] = *(const uint2*)(zrl + zo3);
        mref = mrl[0];
    };

    // ---- warm loop: 16 steps, parity-pair per iteration ----
    for (int i = 0; i < WARM / 2; ++i) {
        const int st = -WARM + 2 * i;
        body(zb0, mb0, zrow,      mrow,     st,     false, true);
        body(zb1, mb1, zrow + 64, mrow + 1, st + 1, false, true);
        zrow += 128; mrow += 2;
    }

    // ---- main loop: 8 steps, fully unrolled ----
    #pragma unroll
    for (int st = 0; st < S_LEN; ++st) {
        if ((st & 1) == 0)
            body(zb0, mb0, zrow + st * 64, mrow + st, st, st >= 1, st == 0);
        else
            body(zb1, mb1, zrow + st * 64, mrow + st, st, true, false);
    }

    // tail flush: means for step S_LEN-1
    {
        f32x4 a2 = {0.f, 0.f, 0.f, 0.f};
        a2 = __builtin_amdgcn_mfma_f32_16x16x32_bf16(wmf[0], hB[0], a2, 0, 0, 0);
        a2 = __builtin_amdgcn_mfma_f32_16x16x32_bf16(wmf[1], hB[1], a2, 0, 0, 0);
        if (q == 0) {
            const size_t tp = (size_t)c * S_LEN + (S_LEN - 1);
            *(float4*)(out + tp * 4) =
                make_float4(a2[0] + bmv.x, a2[1] + bmv.y, a2[2] + bmv.z, a2[3] + bmv.w);
        }
    }
}

extern "C" void kernel_launch(void* const* d_in, const int* in_sizes, int n_in,
                              void* d_out, int out_size, void* d_ws, size_t ws_size,
                              hipStream_t stream) {
    const float* x     = (const float*)d_in[0];
    const float* W1    = (const float*)d_in[1];
    const float* b1    = (const float*)d_in[2];
    const float* W2    = (const float*)d_in[3];
    const float* b2    = (const float*)d_in[4];
    const float* Wx    = (const float*)d_in[5];
    const float* Wh    = (const float*)d_in[6];
    const float* b_rnn = (const float*)d_in[7];
    const float* Wm    = (const float*)d_in[8];
    const float* bm    = (const float*)d_in[9];
    float* out = (float*)d_out;

    // Workspace layout (front-padded by WARM rows; pad contents = poison, OK):
    //   z_pad: (WARM + T + ZPAD_TAIL) rows x 64 bf16
    //   m_pad: (WARM + T + ZPAD_TAIL) floats
    unsigned short* z_pad = (unsigned short*)d_ws;
    const size_t z_rows   = (size_t)(WARM + T_LEN + ZPAD_TAIL);
    float*          m_pad = (float*)((char*)d_ws + z_rows * H * 2);

    unsigned short* z_s = z_pad + (size_t)WARM * H;   // abs t=0 row
    float*          m_s = m_pad + WARM;

    encoder_kernel<<<T_LEN / 256, 256, 0, stream>>>(x, W1, b1, W2, b2, Wx, b_rnn, z_s, m_s);
    rnn_kernel<<<NWAVE / 4, 256, 0, stream>>>(z_pad, m_pad, Wh, Wm, bm, out);
}

// Round 4
// 128.219 us; speedup vs baseline: 1.1708x; 1.0128x over previous
//
#include <hip/hip_runtime.h>
#include <hip/hip_bf16.h>

// Problem constants (B=1)
constexpr int T_LEN  = 262144;
constexpr int H      = 64;
constexpr int S_LEN  = 8;                  // R13-validated
constexpr int WARM   = 16;                 // warm-up steps (contraction ~0.56/step -> 0.56^16 ~ 9e-5 << bf16-h floor)
constexpr int CHUNKS = T_LEN / S_LEN;      // 32768
constexpr int NWAVE  = CHUNKS / 16;        // 2048 RNN waves
constexpr int ZPAD_TAIL = 4;               // rows past T for harmless over-prefetch

typedef __attribute__((ext_vector_type(8))) short short8;  // 8 bf16 (4 VGPRs) MFMA A/B frag
typedef __attribute__((ext_vector_type(4))) float f32x4;   // MFMA C/D frag

// Saturation-safe fast tanh: 1 - 2/(exp(2x)+1). exp overflow -> rcp(inf)=0 -> 1. No NaN.
__device__ __forceinline__ float fast_tanh(float x) {
    float e = __expf(2.0f * x);
    return 1.0f - 2.0f * __builtin_amdgcn_rcpf(e + 1.0f);
}
// bf16 round-to-nearest-even pack / unpack (scalar fallback)
__device__ __forceinline__ unsigned short f2bf(float v) {
    unsigned u = __builtin_bit_cast(unsigned, v);
    return (unsigned short)((u + 0x7fffu + ((u >> 16) & 1u)) >> 16);
}
__device__ __forceinline__ float bf2f(unsigned short b) {
    return __builtin_bit_cast(float, (unsigned)b << 16);
}
// RNE pack of two floats -> packed bf16x2 (1-instruction v_cvt_pk_bf16_f32 when available)
__device__ __forceinline__ unsigned pack2(float a, float b) {
#if __has_builtin(__builtin_amdgcn_cvt_pk_bf16_f32)
    typedef __attribute__((ext_vector_type(2))) __bf16 bf16x2;
    bf16x2 r = __builtin_amdgcn_cvt_pk_bf16_f32(a, b);
    return __builtin_bit_cast(unsigned, r);
#else
    return (unsigned)f2bf(a) | ((unsigned)f2bf(b) << 16);
#endif
}

// ---------------------------------------------------------------------------
// K1 (R14): pi-chained TRANSPOSED encoder — zero scratch LDS, zero in-loop
// barriers. Computes h^T = Wpi^T @ x^T per layer: with weight OUTPUT rows
// pre-permuted by pi(16*mt + 4*q + r) = 32*(mt>>1) + 8*q + 4*(mt&1) + r
// (the R13-validated identity), each layer's packed (pack2) MFMA D output IS
// the next layer's B-fragment in standard k-order. The old per-iter chain of
// 5 LDS round-trips + 4 wave_barriers (L1->pre->A2->L2->pre->A3->L3->pre->out)
// collapses to: xB pack -> L1 -> tanh/pack -> L2 -> tanh/pack -> L3 -> pack
// -> 2 uint4 stores. z lands per lane as features [8q,8q+8) and [32+8q,+8)
// of t = n15-row -> natural [t][64] layout, identical to before (rnn's zo
// offsets are exactly these runs). Dekker split keeps hi in k=0..7 and lo in
// k=8..15 of the SAME K=32 MFMA with the same chain order -> bit-exact;
// absmax must remain 0.001464844.
// ---------------------------------------------------------------------------
__global__ __launch_bounds__(256) void encoder_kernel(
    const float* __restrict__ x,
    const float* __restrict__ W1, const float* __restrict__ b1,
    const float* __restrict__ W2, const float* __restrict__ b2,
    const float* __restrict__ Wx, const float* __restrict__ b_rnn,
    unsigned short* __restrict__ z_s, float* __restrict__ m_s)
{
    __shared__ uint4 w1a[4 * 64];   // pi-rows W1^T A-frags (K=32: q<2 = hi/lo weights, q>=2 zero)
    __shared__ uint4 w2a[8 * 64];   // pi-rows W2^T A-frags (K=64: 2 k-halves)
    __shared__ uint4 w3a[8 * 64];   // pi-rows Wx^T A-frags

    const int tid = threadIdx.x;
    const int w   = tid >> 6;
    const int l   = tid & 63;
    const int q   = l >> 4;
    const int n15 = l & 15;

    // ---- stage pi-permuted W^T A-fragments (RNE bf16), one entry per (tile, lane) ----
    {
        const int smt = tid >> 6;        // tile 0..3
        const int sl  = tid & 63;        // lane slot
        const int sq  = sl >> 4;
        const int sn  = sl & 15;
        const int prow = 32 * (smt >> 1) + 8 * (sn >> 2) + 4 * (smt & 1) + (sn & 3);

        // W1: A[16*smt+sn][k=sq*8+j] ; k in [0,16) = Dekker hi/lo sharing W1 rows, rest 0
        uint4 o1 = make_uint4(0, 0, 0, 0);
        if (sq < 2) {
            float v[8];
            #pragma unroll
            for (int j = 0; j < 8; ++j) v[j] = W1[j * 64 + prow];
            o1.x = pack2(v[0], v[1]); o1.y = pack2(v[2], v[3]);
            o1.z = pack2(v[4], v[5]); o1.w = pack2(v[6], v[7]);
        }
        w1a[smt * 64 + sl] = o1;

        #pragma unroll
        for (int kh = 0; kh < 2; ++kh) {
            float v2[8], v3[8];
            #pragma unroll
            for (int j = 0; j < 8; ++j) {
                const int k = kh * 32 + sq * 8 + j;
                v2[j] = W2[k * 64 + prow];
                v3[j] = Wx[k * 64 + prow];
            }
            uint4 o2, o3;
            o2.x = pack2(v2[0], v2[1]); o2.y = pack2(v2[2], v2[3]);
            o2.z = pack2(v2[4], v2[5]); o2.w = pack2(v2[6], v2[7]);
            o3.x = pack2(v3[0], v3[1]); o3.y = pack2(v3[2], v3[3]);
            o3.z = pack2(v3[4], v3[5]); o3.w = pack2(v3[6], v3[7]);
            w2a[(smt * 2 + kh) * 64 + sl] = o2;
            w3a[(smt * 2 + kh) * 64 + sl] = o3;
        }
    }
    __syncthreads();

    // biases per lane, float4 per tile: feature base = 32*(mt>>1) + 4*(mt&1) + 8q
    f32x4 b1v[4], b2v[4], brv[4];
    #pragma unroll
    for (int mt = 0; mt < 4; ++mt) {
        const int base = 32 * (mt >> 1) + 4 * (mt & 1) + 8 * q;
        b1v[mt] = *(const f32x4*)(b1 + base);
        b2v[mt] = *(const f32x4*)(b2 + base);
        brv[mt] = *(const f32x4*)(b_rnn + base);
    }

    // prefetch iter 0's x row (t = n15 within this wave's 16-row group)
    float4 xa, xb;
    {
        const size_t t0 = (size_t)(blockIdx.x * 256 + w * 16 + n15) * 8;
        xa = *(const float4*)(x + t0);
        xb = *(const float4*)(x + t0 + 4);
    }

    #pragma unroll
    for (int it = 0; it < 4; ++it) {
        const int t = blockIdx.x * 256 + it * 64 + w * 16 + n15;

        // issue iter+1's x load NOW
        float4 na = xa, nb = xb;
        if (it < 3) {
            const size_t tn0 = (size_t)(t + 64) * 8;
            na = *(const float4*)(x + tn0);
            nb = *(const float4*)(x + tn0 + 4);
        }

        // ---- x^T B-frag, Dekker-split: q=0 -> hi (k 0..7), q=1 -> lo (k 8..15) ----
        short8 xB = (short8)0;
        {
            const float xv[8] = {xa.x, xa.y, xa.z, xa.w, xb.x, xb.y, xb.z, xb.w};
            if (q == 0) {
                bool nz = false;
                #pragma unroll
                for (int d = 0; d < 8; ++d) nz = nz || (xv[d] != 0.0f);
                m_s[t] = nz ? 1.0f : 0.0f;
                uint4 o;
                o.x = pack2(xv[0], xv[1]); o.y = pack2(xv[2], xv[3]);
                o.z = pack2(xv[4], xv[5]); o.w = pack2(xv[6], xv[7]);
                xB = __builtin_bit_cast(short8, o);
            } else if (q == 1) {
                float lo[8];
                #pragma unroll
                for (int d = 0; d < 8; ++d) lo[d] = xv[d] - bf2f(f2bf(xv[d]));
                uint4 o;
                o.x = pack2(lo[0], lo[1]); o.y = pack2(lo[2], lo[3]);
                o.z = pack2(lo[4], lo[5]); o.w = pack2(lo[6], lo[7]);
                xB = __builtin_bit_cast(short8, o);
            }
        }

        // ---- L1: h1^T(pi) = W1pi^T @ x^T ----
        f32x4 acc[4];
        #pragma unroll
        for (int mt = 0; mt < 4; ++mt)
            acc[mt] = __builtin_amdgcn_mfma_f32_16x16x32_bf16(
                __builtin_bit_cast(short8, w1a[mt * 64 + l]), xB,
                (f32x4){0.f, 0.f, 0.f, 0.f}, 0, 0, 0);

        // tanh + b1 -> packed B-frags (D-to-B identity: word (mt&1)*2+{0,1} of half mt>>1)
        short8 hb0, hb1;
        {
            unsigned hw[8];
            #pragma unroll
            for (int mt = 0; mt < 4; ++mt) {
                float th[4];
                #pragma unroll
                for (int r = 0; r < 4; ++r)
                    th[r] = fast_tanh(acc[mt][r] + b1v[mt][r]);
                hw[mt * 2 + 0] = pack2(th[0], th[1]);
                hw[mt * 2 + 1] = pack2(th[2], th[3]);
            }
            hb0 = __builtin_bit_cast(short8, make_uint4(hw[0], hw[1], hw[2], hw[3]));
            hb1 = __builtin_bit_cast(short8, make_uint4(hw[4], hw[5], hw[6], hw[7]));
        }

        // ---- L2: h2^T(pi) = W2pi^T @ h1^T ----
        #pragma unroll
        for (int mt = 0; mt < 4; ++mt) {
            f32x4 d = {0.f, 0.f, 0.f, 0.f};
            d = __builtin_amdgcn_mfma_f32_16x16x32_bf16(
                    __builtin_bit_cast(short8, w2a[(mt * 2 + 0) * 64 + l]), hb0, d, 0, 0, 0);
            d = __builtin_amdgcn_mfma_f32_16x16x32_bf16(
                    __builtin_bit_cast(short8, w2a[(mt * 2 + 1) * 64 + l]), hb1, d, 0, 0, 0);
            acc[mt] = d;
        }
        {
            unsigned hw[8];
            #pragma unroll
            for (int mt = 0; mt < 4; ++mt) {
                float th[4];
                #pragma unroll
                for (int r = 0; r < 4; ++r)
                    th[r] = fast_tanh(acc[mt][r] + b2v[mt][r]);
                hw[mt * 2 + 0] = pack2(th[0], th[1]);
                hw[mt * 2 + 1] = pack2(th[2], th[3]);
            }
            hb0 = __builtin_bit_cast(short8, make_uint4(hw[0], hw[1], hw[2], hw[3]));
            hb1 = __builtin_bit_cast(short8, make_uint4(hw[4], hw[5], hw[6], hw[7]));
        }

        // ---- L3: z^T(pi) = Wxpi^T @ h2^T + b_rnn ----
        #pragma unroll
        for (int mt = 0; mt < 4; ++mt) {
            f32x4 d = {0.f, 0.f, 0.f, 0.f};
            d = __builtin_amdgcn_mfma_f32_16x16x32_bf16(
                    __builtin_bit_cast(short8, w3a[(mt * 2 + 0) * 64 + l]), hb0, d, 0, 0, 0);
            d = __builtin_amdgcn_mfma_f32_16x16x32_bf16(
                    __builtin_bit_cast(short8, w3a[(mt * 2 + 1) * 64 + l]), hb1, d, 0, 0, 0);
            acc[mt] = d;
        }

        // ---- z -> RNE bf16, natural [t][64]: lane holds feats [8q,8q+8) and [32+8q,+8) ----
        {
            unsigned zw[8];
            #pragma unroll
            for (int mt = 0; mt < 4; ++mt) {
                float z0 = acc[mt][0] + brv[mt][0];
                float z1 = acc[mt][1] + brv[mt][1];
                float z2 = acc[mt][2] + brv[mt][2];
                float z3 = acc[mt][3] + brv[mt][3];
                zw[mt * 2 + 0] = pack2(z0, z1);
                zw[mt * 2 + 1] = pack2(z2, z3);
            }
            unsigned short* dst = z_s + (size_t)t * 64 + 8 * q;
            *(uint4*)(dst)      = make_uint4(zw[0], zw[1], zw[2], zw[3]);
            *(uint4*)(dst + 32) = make_uint4(zw[4], zw[5], zw[6], zw[7]);
        }

        xa = na; xb = nb;
    }
}

// ---------------------------------------------------------------------------
// K2: R13 rnn_kernel, UNCHANGED (validated bit-exact; absmax tripwire).
// ---------------------------------------------------------------------------
__global__ __launch_bounds__(256) void rnn_kernel(
    const unsigned short* __restrict__ z_pad, const float* __restrict__ m_pad,
    const float* __restrict__ Wh, const float* __restrict__ Wm,
    const float* __restrict__ bm, float* __restrict__ out)
{
    const int tid = threadIdx.x;
    const int w   = tid >> 6;
    const int l   = tid & 63;
    const int q   = l >> 4;
    const int n15 = l & 15;
    const int rw  = blockIdx.x * 4 + w;   // global wave id
    const int c   = rw * 16 + n15;        // this lane's chunk (D/B col n = n15)

    // pi-permuted Wh^T A-fragments
    short8 afrag[8];
    #pragma unroll
    for (int tn = 0; tn < 4; ++tn) {
        const int prow = 32 * (tn >> 1) + 8 * (n15 >> 2) + 4 * (tn & 1) + (n15 & 3);
        #pragma unroll
        for (int kh = 0; kh < 2; ++kh) {
            short8 s;
            #pragma unroll
            for (int j = 0; j < 8; ++j)
                s[j] = (short)f2bf(Wh[(kh * 32 + q * 8 + j) * 64 + prow]);
            afrag[tn * 2 + kh] = s;
        }
    }
    // Wm^T A-fragment: rows 0..3 valid (mean index), rest zero
    short8 wmf[2];
    #pragma unroll
    for (int kh = 0; kh < 2; ++kh) {
        short8 s;
        #pragma unroll
        for (int j = 0; j < 8; ++j)
            s[j] = (n15 < 4) ? (short)f2bf(Wm[(kh * 32 + q * 8 + j) * 4 + n15]) : (short)0;
        wmf[kh] = s;
    }
    const float4 bmv = *(const float4*)bm;   // bm[0..3], used by q==0 lanes

    // h state: ONLY the bf16 B-frags. hB[half] element j = h[chunk n15][feat half*32+8q+j].
    short8 hB[2];
    hB[0] = (short8)0;
    hB[1] = (short8)0;

    // per-lane linear pointers into the PADDED arrays (padded row 0 = abs t -WARM)
    const unsigned short* zrow = z_pad + (size_t)c * S_LEN * 64;
    const float*          mrow = m_pad + (size_t)c * S_LEN;
    const int tneg = -(c * S_LEN);        // st at which abs t == 0

    // z load offset for acc-tile tn under pi: feat base = 32*(tn>>1) + 8q + 4*(tn&1)
    const int zo0 = 8 * q;            // tn=0
    const int zo1 = 8 * q + 4;        // tn=1
    const int zo2 = 8 * q + 32;       // tn=2
    const int zo3 = 8 * q + 36;       // tn=3

    // preload steps st=-WARM (parity 0) and st=-WARM+1 (parity 1)
    uint2 zb0[4], zb1[4];
    float mb0, mb1;
    {
        zb0[0] = *(const uint2*)(zrow + zo0);
        zb0[1] = *(const uint2*)(zrow + zo1);
        zb0[2] = *(const uint2*)(zrow + zo2);
        zb0[3] = *(const uint2*)(zrow + zo3);
        zb1[0] = *(const uint2*)(zrow + 64 + zo0);
        zb1[1] = *(const uint2*)(zrow + 64 + zo1);
        zb1[2] = *(const uint2*)(zrow + 64 + zo2);
        zb1[3] = *(const uint2*)(zrow + 64 + zo3);
    }
    mb0 = mrow[0];
    mb1 = mrow[1];
    zrow += 128; mrow += 2;               // -> reload row for st=-WARM (i.e. st+2)

    // body: consume (zbuf,mref) for step st, then reload them from (zrl,mrl) = st+2
    auto body = [&](uint2* zbuf, float& mref,
                    const unsigned short* zrl, const float* mrl,
                    int stv, bool means_prev, bool may_reset) {
        if (may_reset && rw == 0) {       // uniform branch: 2047/2048 waves skip
            if (stv == tneg) {            // per-lane (tneg depends on n15)
                hB[0] = (short8)0; hB[1] = (short8)0;
            }
        }
        // preact^T(pi) = pi-rows(Wh^T) @ h^T
        f32x4 acc[4];
        #pragma unroll
        for (int mt = 0; mt < 4; ++mt) {
            f32x4 d = {0.f, 0.f, 0.f, 0.f};
            d = __builtin_amdgcn_mfma_f32_16x16x32_bf16(afrag[mt * 2 + 0], hB[0], d, 0, 0, 0);
            d = __builtin_amdgcn_mfma_f32_16x16x32_bf16(afrag[mt * 2 + 1], hB[1], d, 0, 0, 0);
            acc[mt] = d;
        }
        // means of the PREVIOUS step's h (hB not yet updated)
        if (means_prev) {
            f32x4 a2 = {0.f, 0.f, 0.f, 0.f};
            a2 = __builtin_amdgcn_mfma_f32_16x16x32_bf16(wmf[0], hB[0], a2, 0, 0, 0);
            a2 = __builtin_amdgcn_mfma_f32_16x16x32_bf16(wmf[1], hB[1], a2, 0, 0, 0);
            if (q == 0) {
                const size_t tp = (size_t)c * S_LEN + (stv - 1);
                *(float4*)(out + tp * 4) =
                    make_float4(a2[0] + bmv.x, a2[1] + bmv.y, a2[2] + bmv.z, a2[3] + bmv.w);
            }
        }
        // z add + tanh + pack straight into hB; mask-carry on packed words.
        const bool upd = (mref != 0.0f);
        #pragma unroll
        for (int tn = 0; tn < 4; ++tn) {
            const unsigned short* zp = (const unsigned short*)&zbuf[tn];
            float th[4];
            #pragma unroll
            for (int r = 0; r < 4; ++r)
                th[r] = fast_tanh(acc[tn][r] + bf2f(zp[r]));
            const unsigned w0 = pack2(th[0], th[1]);
            const unsigned w1 = pack2(th[2], th[3]);
            unsigned* hw = (unsigned*)&hB[tn >> 1];
            const int wi = (tn & 1) * 2;
            hw[wi + 0] = upd ? w0 : hw[wi + 0];
            hw[wi + 1] = upd ? w1 : hw[wi + 1];
        }
        // reload this parity's buffers for step st+2 (wait lands a full body later)
        zbuf[0] = *(const uint2*)(zrl + zo0);
        zbuf[1] = *(const uint2*)(zrl + zo1);
        zbuf[2] = *(const uint2*)(zrl + zo2);
        zbuf[3] = *(const uint2*)(zrl + zo3);
        mref = mrl[0];
    };

    // ---- warm loop: 16 steps, parity-pair per iteration ----
    for (int i = 0; i < WARM / 2; ++i) {
        const int st = -WARM + 2 * i;
        body(zb0, mb0, zrow,      mrow,     st,     false, true);
        body(zb1, mb1, zrow + 64, mrow + 1, st + 1, false, true);
        zrow += 128; mrow += 2;
    }

    // ---- main loop: 8 steps, fully unrolled ----
    #pragma unroll
    for (int st = 0; st < S_LEN; ++st) {
        if ((st & 1) == 0)
            body(zb0, mb0, zrow + st * 64, mrow + st, st, st >= 1, st == 0);
        else
            body(zb1, mb1, zrow + st * 64, mrow + st, st, true, false);
    }

    // tail flush: means for step S_LEN-1
    {
        f32x4 a2 = {0.f, 0.f, 0.f, 0.f};
        a2 = __builtin_amdgcn_mfma_f32_16x16x32_bf16(wmf[0], hB[0], a2, 0, 0, 0);
        a2 = __builtin_amdgcn_mfma_f32_16x16x32_bf16(wmf[1], hB[1], a2, 0, 0, 0);
        if (q == 0) {
            const size_t tp = (size_t)c * S_LEN + (S_LEN - 1);
            *(float4*)(out + tp * 4) =
                make_float4(a2[0] + bmv.x, a2[1] + bmv.y, a2[2] + bmv.z, a2[3] + bmv.w);
        }
    }
}

extern "C" void kernel_launch(void* const* d_in, const int* in_sizes, int n_in,
                              void* d_out, int out_size, void* d_ws, size_t ws_size,
                              hipStream_t stream) {
    const float* x     = (const float*)d_in[0];
    const float* W1    = (const float*)d_in[1];
    const float* b1    = (const float*)d_in[2];
    const float* W2    = (const float*)d_in[3];
    const float* b2    = (const float*)d_in[4];
    const float* Wx    = (const float*)d_in[5];
    const float* Wh    = (const float*)d_in[6];
    const float* b_rnn = (const float*)d_in[7];
    const float* Wm    = (const float*)d_in[8];
    const float* bm    = (const float*)d_in[9];
    float* out = (float*)d_out;

    // Workspace layout (front-padded by WARM rows; pad contents = poison, OK):
    //   z_pad: (WARM + T + ZPAD_TAIL) rows x 64 bf16
    //   m_pad: (WARM + T + ZPAD_TAIL) floats
    unsigned short* z_pad = (unsigned short*)d_ws;
    const size_t z_rows   = (size_t)(WARM + T_LEN + ZPAD_TAIL);
    float*          m_pad = (float*)((char*)d_ws + z_rows * H * 2);

    unsigned short* z_s = z_pad + (size_t)WARM * H;   // abs t=0 row
    float*          m_s = m_pad + WARM;

    encoder_kernel<<<T_LEN / 256, 256, 0, stream>>>(x, W1, b1, W2, b2, Wx, b_rnn, z_s, m_s);
    rnn_kernel<<<NWAVE / 4, 256, 0, stream>>>(z_pad, m_pad, Wh, Wm, bm, out);
}